// Round 1
// baseline (122.851 us; speedup 1.0000x reference)
//
#include <hip/hip_runtime.h>
#include <cmath>

namespace {

constexpr int B_ = 128;
constexpr int N_ = 64;
constexpr int T_ = 512;
constexpr int K_ = 5;
constexpr int NBINS = 257;   // T/2 + 1
constexpr int PMAX = 2184;   // T*T // 120
constexpr int NCHUNK = 32;   // channels per DFT block

// ---------------- Kernel A: DFT magnitudes (partial sums over channel chunk) ----
// grid = (B_*2), block = 256. Each block: batch b, channels [chunk*32, chunk*32+32).
// Thread tid owns frequency bin (tid+1). magp[bx][bin] = sum_n |F[b,n,bin]|.
__global__ __launch_bounds__(256) void dft_mag_kernel(const float* __restrict__ x,
                                                      float* __restrict__ magp) {
  const int bx = blockIdx.x;
  const int b = bx >> 1;
  const int nbase = (bx & 1) * NCHUNK;
  const int tid = threadIdx.x;

  // transposed stage: xs[t][n], pad 36 to break bank collisions on write
  __shared__ __align__(16) float xs[T_][36];

  for (int nn = 0; nn < NCHUNK; ++nn) {
    const float* src = x + (((size_t)(b * N_ + nbase + nn)) << 9);
    for (int t = tid; t < T_; t += 256) xs[t][nn] = src[t];
  }
  __syncthreads();

  const int ibin = tid + 1;  // bins 1..256 (bin 0 is zeroed by reference)
  float re[NCHUNK], im[NCHUNK];
#pragma unroll
  for (int q = 0; q < NCHUNK; ++q) { re[q] = 0.0f; im[q] = 0.0f; }

  const float w = 6.2831853071795864769f / 512.0f;
  int j = 0;  // (t * ibin) & 511, kept incrementally
  for (int t = 0; t < T_; ++t) {
    float sn, cs;
    __sincosf((float)j * w, &sn, &cs);
    const float* row = &xs[t][0];
#pragma unroll
    for (int q = 0; q < 8; ++q) {
      const float4 v = *reinterpret_cast<const float4*>(row + (q << 2));
      re[4*q+0] += v.x * cs; im[4*q+0] += v.x * sn;
      re[4*q+1] += v.y * cs; im[4*q+1] += v.y * sn;
      re[4*q+2] += v.z * cs; im[4*q+2] += v.z * sn;
      re[4*q+3] += v.w * cs; im[4*q+3] += v.w * sn;
    }
    j = (j + ibin) & 511;
  }

  float acc = 0.0f;
#pragma unroll
  for (int q = 0; q < NCHUNK; ++q) acc += sqrtf(re[q]*re[q] + im[q]*im[q]);
  magp[(size_t)bx * NBINS + ibin] = acc;
}

// ---------------- Kernel B: per-batch top-5 -> window sizes -------------------
// grid = B_, block = 64 (one wave). Replicates jax.lax.top_k ordering
// (descending value, ties -> lower index).
__global__ __launch_bounds__(64) void topk_scale_kernel(const float* __restrict__ magp,
                                                        int* __restrict__ scale) {
  const int b = blockIdx.x;
  const int lane = threadIdx.x;
  __shared__ float m[NBINS];
  for (int i = lane; i < NBINS; i += 64) {
    m[i] = (i == 0) ? -1.0f
                    : magp[(size_t)(b * 2) * NBINS + i] +
                      magp[(size_t)(b * 2 + 1) * NBINS + i];
  }
  __syncthreads();

  for (int kk = 0; kk < K_; ++kk) {
    float best = -1e30f;
    int bi = NBINS;
    for (int i = lane; i < NBINS; i += 64) {
      const float v = m[i];
      if (v > best || (v == best && i < bi)) { best = v; bi = i; }
    }
    for (int off = 32; off > 0; off >>= 1) {
      const float ov = __shfl_down(best, off);
      const int oi = __shfl_down(bi, off);
      if (ov > best || (ov == best && oi < bi)) { best = ov; bi = oi; }
    }
    bi = __shfl(bi, 0);
    if (lane == 0) {
      // scale = floor(512 / (i * 15/64)) = 32768 / (15*i), exact (see analysis)
      int sc = 32768 / (15 * bi);
      sc = sc < 1 ? 1 : (sc > PMAX ? PMAX : sc);
      scale[b * K_ + kk] = sc;
      m[bi] = -1e30f;  // remove for next extraction
    }
    __syncthreads();
  }
}

// ---------------- Kernel C: prefix sum + windowed means -----------------------
// grid = B_*N_, block = 256. One block per (b, n) row.
__global__ __launch_bounds__(256) void trend_kernel(const float* __restrict__ x,
                                                    const int* __restrict__ scale,
                                                    float* __restrict__ out) {
  const int bn = blockIdx.x;  // b*64 + n
  const int b = bn >> 6;
  const int tid = threadIdx.x;

  __shared__ double bufA[T_];
  __shared__ double bufB[T_];
  __shared__ double P[T_ + 1];

  const float* src = x + ((size_t)bn << 9);
  for (int t = tid; t < T_; t += 256) bufA[t] = (double)src[t];
  __syncthreads();

  // Hillis-Steele inclusive scan in f64 (ping-pong)
  double* s = bufA;
  double* d = bufB;
  for (int off = 1; off < T_; off <<= 1) {
    for (int t = tid; t < T_; t += 256) {
      double v = s[t];
      if (t >= off) v += s[t - off];
      d[t] = v;
    }
    __syncthreads();
    double* tmp = s; s = d; d = tmp;
  }
  for (int t = tid; t < T_; t += 256) P[t + 1] = s[t];
  if (tid == 0) P[0] = 0.0;
  __syncthreads();

  const double x0 = (double)src[0];
  const double xl = (double)src[T_ - 1];

  float* outbn = out + (((size_t)bn * K_) << 9);
#pragma unroll
  for (int kk = 0; kk < K_; ++kk) {
    const int k = scale[b * K_ + kk];
    const int p = (k - 1) >> 1;
    const int Lm1 = T_ + 2 * p - k;  // L - 1
    const double invk = 1.0 / (double)k;
    for (int t = tid; t < T_; t += 256) {
      const int tc = t < Lm1 ? t : Lm1;
      const int lo = tc - p;       // window = [lo, lo+k) in original coords
      const int hi = lo + k;
      const int cl = lo < 0 ? -lo : 0;        // left edge replications of x0
      const int cr = hi > T_ ? hi - T_ : 0;   // right edge replications of x511
      const int loc = lo < 0 ? 0 : lo;        // lo <= 511 always
      const int hic = hi > T_ ? T_ : hi;      // hi >= 1 always
      const double sum = P[hic] - P[loc] + (double)cl * x0 + (double)cr * xl;
      outbn[(kk << 9) + t] = (float)(sum * invk);
    }
  }
}

}  // namespace

extern "C" void kernel_launch(void* const* d_in, const int* in_sizes, int n_in,
                              void* d_out, int out_size, void* d_ws, size_t ws_size,
                              hipStream_t stream) {
  const float* x = (const float*)d_in[0];
  float* out = (float*)d_out;

  // mag partials live in d_out (256*257 floats = 263 KB); kernel C fully
  // overwrites d_out afterwards in stream order, so this is safe scratch.
  float* magp = out;
  // scale (128*5 ints = 2.5 KB) in d_ws: must survive while C runs.
  int* scale = (int*)d_ws;

  hipLaunchKernelGGL(dft_mag_kernel, dim3(B_ * 2), dim3(256), 0, stream, x, magp);
  hipLaunchKernelGGL(topk_scale_kernel, dim3(B_), dim3(64), 0, stream, magp, scale);
  hipLaunchKernelGGL(trend_kernel, dim3(B_ * N_), dim3(256), 0, stream, x, scale, out);
}

// Round 2
// 120.884 us; speedup vs baseline: 1.0163x; 1.0163x over previous
//
#include <hip/hip_runtime.h>
#include <cmath>

namespace {

constexpr int B_ = 128;
constexpr int N_ = 64;
constexpr int T_ = 512;
constexpr int K_ = 5;
constexpr int NBINS = 257;   // T/2 + 1
constexpr int PMAX = 2184;   // T*T // 120
constexpr int NCHUNK = 8;    // channels per DFT block
constexpr int NCHK = N_ / NCHUNK;  // 8 chunks per batch

// ---------------- Kernel A: DFT magnitudes (partial sums over 8-channel chunk) --
// grid = B_*8, block = 256. Thread tid owns frequency bin (tid+1).
// magp[bx][bin] = sum over the chunk's channels of |F[b,n,bin]|.
// Twiddles: incremental rotation by (c0,s0), re-synced via __sincosf every 32 t.
__global__ __launch_bounds__(256) void dft_mag_kernel(const float* __restrict__ x,
                                                      float* __restrict__ magp) {
  const int bx = blockIdx.x;
  const int b = bx >> 3;
  const int nbase = (bx & 7) * NCHUNK;
  const int tid = threadIdx.x;

  __shared__ __align__(16) float xs[T_][NCHUNK];  // 16 KB

  for (int nn = 0; nn < NCHUNK; ++nn) {
    const float* src = x + (((size_t)(b * N_ + nbase + nn)) << 9);
    for (int t = tid; t < T_; t += 256) xs[t][nn] = src[t];
  }
  __syncthreads();

  const int ibin = tid + 1;  // bins 1..256 (bin 0 zeroed by reference)
  float re[NCHUNK], im[NCHUNK];
#pragma unroll
  for (int q = 0; q < NCHUNK; ++q) { re[q] = 0.0f; im[q] = 0.0f; }

  const float w = 6.2831853071795864769f / 512.0f;
  float c0, s0;
  __sincosf((float)ibin * w, &s0, &c0);  // per-step rotation

  int j = 0;  // (t * ibin) & 511 at group start
  for (int t0 = 0; t0 < T_; t0 += 32) {
    float sn, cs;
    __sincosf((float)j * w, &sn, &cs);  // exact resync each group
#pragma unroll
    for (int u = 0; u < 32; ++u) {
      const float* row = &xs[t0 + u][0];
      const float4 v0 = *reinterpret_cast<const float4*>(row);
      const float4 v1 = *reinterpret_cast<const float4*>(row + 4);
      re[0] += v0.x * cs; im[0] += v0.x * sn;
      re[1] += v0.y * cs; im[1] += v0.y * sn;
      re[2] += v0.z * cs; im[2] += v0.z * sn;
      re[3] += v0.w * cs; im[3] += v0.w * sn;
      re[4] += v1.x * cs; im[4] += v1.x * sn;
      re[5] += v1.y * cs; im[5] += v1.y * sn;
      re[6] += v1.z * cs; im[6] += v1.z * sn;
      re[7] += v1.w * cs; im[7] += v1.w * sn;
      const float ncs = cs * c0 - sn * s0;
      const float nsn = sn * c0 + cs * s0;
      cs = ncs; sn = nsn;
    }
    j = (j + (ibin << 5)) & 511;
  }

  float acc = 0.0f;
#pragma unroll
  for (int q = 0; q < NCHUNK; ++q) acc += sqrtf(re[q] * re[q] + im[q] * im[q]);
  magp[(size_t)bx * NBINS + ibin] = acc;
}

// ---------------- Kernel B: per-batch top-5 -> window sizes -------------------
// grid = B_, block = 64 (one wave). Replicates jax.lax.top_k ordering
// (descending value, ties -> lower index).
__global__ __launch_bounds__(64) void topk_scale_kernel(const float* __restrict__ magp,
                                                        int* __restrict__ scale) {
  const int b = blockIdx.x;
  const int lane = threadIdx.x;
  __shared__ float m[NBINS];
  for (int i = lane; i < NBINS; i += 64) {
    float s = -1.0f;
    if (i != 0) {
      s = 0.0f;
      for (int c = 0; c < NCHK; ++c)
        s += magp[(size_t)(b * NCHK + c) * NBINS + i];
    }
    m[i] = s;
  }
  __syncthreads();

  for (int kk = 0; kk < K_; ++kk) {
    float best = -1e30f;
    int bi = NBINS;
    for (int i = lane; i < NBINS; i += 64) {
      const float v = m[i];
      if (v > best || (v == best && i < bi)) { best = v; bi = i; }
    }
    for (int off = 32; off > 0; off >>= 1) {
      const float ov = __shfl_down(best, off);
      const int oi = __shfl_down(bi, off);
      if (ov > best || (ov == best && oi < bi)) { best = ov; bi = oi; }
    }
    bi = __shfl(bi, 0);
    if (lane == 0) {
      // scale = floor(512 / (i * 15/64)) = 32768 / (15*i), exact integer
      int sc = 32768 / (15 * bi);
      sc = sc < 1 ? 1 : (sc > PMAX ? PMAX : sc);
      scale[b * K_ + kk] = sc;
      m[bi] = -1e30f;  // remove for next extraction
    }
    __syncthreads();
  }
}

// ---------------- Kernel C: prefix sum + windowed means -----------------------
// grid = B_*N_, block = 256. One block per (b, n) row.
__global__ __launch_bounds__(256) void trend_kernel(const float* __restrict__ x,
                                                    const int* __restrict__ scale,
                                                    float* __restrict__ out) {
  const int bn = blockIdx.x;  // b*64 + n
  const int b = bn >> 6;
  const int tid = threadIdx.x;

  __shared__ double bufA[T_];
  __shared__ double bufB[T_];
  __shared__ double P[T_ + 1];

  const float* src = x + ((size_t)bn << 9);
  for (int t = tid; t < T_; t += 256) bufA[t] = (double)src[t];
  __syncthreads();

  // Hillis-Steele inclusive scan in f64 (ping-pong)
  double* s = bufA;
  double* d = bufB;
  for (int off = 1; off < T_; off <<= 1) {
    for (int t = tid; t < T_; t += 256) {
      double v = s[t];
      if (t >= off) v += s[t - off];
      d[t] = v;
    }
    __syncthreads();
    double* tmp = s; s = d; d = tmp;
  }
  for (int t = tid; t < T_; t += 256) P[t + 1] = s[t];
  if (tid == 0) P[0] = 0.0;
  __syncthreads();

  const double x0 = (double)src[0];
  const double xl = (double)src[T_ - 1];

  float* outbn = out + (((size_t)bn * K_) << 9);
#pragma unroll
  for (int kk = 0; kk < K_; ++kk) {
    const int k = scale[b * K_ + kk];
    const int p = (k - 1) >> 1;
    const int Lm1 = T_ + 2 * p - k;  // L - 1
    const double invk = 1.0 / (double)k;
    for (int t = tid; t < T_; t += 256) {
      const int tc = t < Lm1 ? t : Lm1;
      const int lo = tc - p;       // window = [lo, lo+k) in original coords
      const int hi = lo + k;
      const int cl = lo < 0 ? -lo : 0;        // left edge replications of x0
      const int cr = hi > T_ ? hi - T_ : 0;   // right edge replications of x511
      const int loc = lo < 0 ? 0 : lo;
      const int hic = hi > T_ ? T_ : hi;
      const double sum = P[hic] - P[loc] + (double)cl * x0 + (double)cr * xl;
      outbn[(kk << 9) + t] = (float)(sum * invk);
    }
  }
}

}  // namespace

extern "C" void kernel_launch(void* const* d_in, const int* in_sizes, int n_in,
                              void* d_out, int out_size, void* d_ws, size_t ws_size,
                              hipStream_t stream) {
  const float* x = (const float*)d_in[0];
  float* out = (float*)d_out;

  // mag partials live in d_out (1024*257 floats = 1.05 MB); kernel C fully
  // overwrites d_out afterwards in stream order, so this is safe scratch.
  float* magp = out;
  // scale (128*5 ints = 2.5 KB) in d_ws: must survive while C runs.
  int* scale = (int*)d_ws;

  hipLaunchKernelGGL(dft_mag_kernel, dim3(B_ * NCHK), dim3(256), 0, stream, x, magp);
  hipLaunchKernelGGL(topk_scale_kernel, dim3(B_), dim3(64), 0, stream, magp, scale);
  hipLaunchKernelGGL(trend_kernel, dim3(B_ * N_), dim3(256), 0, stream, x, scale, out);
}

// Round 3
// 58.282 us; speedup vs baseline: 2.1079x; 2.0741x over previous
//
#include <hip/hip_runtime.h>
#include <cmath>

namespace {

constexpr int B_ = 128;
constexpr int N_ = 64;
constexpr int T_ = 512;
constexpr int K_ = 5;
constexpr int NBINS = 257;   // T/2 + 1
constexpr int PMAX = 2184;   // T*T // 120
constexpr int ROWS = 4;      // (b,n) rows per block, 1 per wave
constexpr int CHUNKS = N_ / ROWS;  // 16 mag-partial chunks per batch

struct cpx { float re, im; };
__device__ __forceinline__ cpx cadd(cpx a, cpx b) { return {a.re + b.re, a.im + b.im}; }
__device__ __forceinline__ cpx csub(cpx a, cpx b) { return {a.re - b.re, a.im - b.im}; }
__device__ __forceinline__ cpx cmul(cpx a, cpx b) {
  return {a.re * b.re - a.im * b.im, a.re * b.im + a.im * b.re};
}

// Full complex radix-8 DFT: t[c] = sum_w z[w] * W8^{w*c}, W8 = e^{-2pi i/8}.
__device__ __forceinline__ void radix8(const cpx z[8], cpx t[8]) {
  const float c = 0.70710678118654752f;
  cpx a0 = cadd(z[0], z[4]), a1 = csub(z[0], z[4]);
  cpx a2 = cadd(z[2], z[6]), a3 = csub(z[2], z[6]);
  cpx a4 = cadd(z[1], z[5]), a5 = csub(z[1], z[5]);
  cpx a6 = cadd(z[3], z[7]), a7 = csub(z[3], z[7]);
  cpx b0 = cadd(a0, a2), b1 = csub(a0, a2);
  cpx b2 = cadd(a4, a6), b3 = csub(a4, a6);
  t[0] = cadd(b0, b2);
  t[4] = csub(b0, b2);
  t[2] = {b1.re + b3.im, b1.im - b3.re};   // b1 - i*b3
  t[6] = {b1.re - b3.im, b1.im + b3.re};   // b1 + i*b3
  cpx ua5  = {c * (a5.re + a5.im), c * (a5.im - a5.re)};  // u*a5,  u = c(1-i)
  cpx usa5 = {c * (a5.re - a5.im), c * (a5.re + a5.im)};  // u"*a5, u" = c(1+i)
  cpx ua7  = {c * (a7.re + a7.im), c * (a7.im - a7.re)};
  cpx usa7 = {c * (a7.re - a7.im), c * (a7.re + a7.im)};
  cpx mia3 = {a3.im, -a3.re};  // -i*a3
  cpx pia3 = {-a3.im, a3.re};  // +i*a3
  t[1] = cadd(cadd(a1, ua5), csub(mia3, usa7));   // a1 + u a5 - i a3 - u" a7
  t[3] = cadd(csub(a1, usa5), cadd(pia3, ua7));   // a1 - u" a5 + i a3 + u a7
  t[5] = cadd(csub(a1, ua5), cadd(mia3, usa7));   // a1 - u a5 - i a3 + u" a7
  t[7] = cadd(cadd(a1, usa5), csub(pia3, ua7));   // a1 + u" a5 + i a3 - u a7
}

// ---------------- Kernel A: radix-8^3 FFT magnitudes --------------------------
// grid = B_*CHUNKS, block = 256 (4 waves, 1 (b,n) row per wave).
// magp[block][bin] = sum over the block's 4 rows of |FFT(x_row)[bin]|, bin 0..256.
// Decomposition (DIF): X[8q+r] = DFT64_j( W512^{jr} * DFT8_v(x[j+64v]) ),
//   DFT64: A[c+8s] = DFT8_i( W64^{ic} * DFT8_w(z[i+8w]) )  ->  k = 64s + 8c + r.
__global__ __launch_bounds__(256) void fft_mag_kernel(const float* __restrict__ x,
                                                      float* __restrict__ magp) {
  const int tid = threadIdx.x;
  const int w = tid >> 6;      // wave = row within block
  const int lane = tid & 63;
  const int row = blockIdx.x * ROWS + w;  // b*64 + n

  __shared__ float buf[ROWS][576 * 2];   // per-wave complex scratch (z then y), pad *9
  __shared__ float magw[ROWS][NBINS];

  // ---- phase 1: real radix-8 over v (stride 64) + twiddle W512^{j*r}
  const float* src = x + ((size_t)row << 9);
  float xv[8];
#pragma unroll
  for (int v = 0; v < 8; ++v) xv[v] = src[lane + (v << 6)];
  {
    const int j = lane;
    const float c = 0.70710678118654752f;
    float s04 = xv[0] + xv[4], d04 = xv[0] - xv[4];
    float s26 = xv[2] + xv[6], d26 = xv[2] - xv[6];
    float s15 = xv[1] + xv[5], d15 = xv[1] - xv[5];
    float s37 = xv[3] + xv[7], d37 = xv[3] - xv[7];
    float se = s04 + s26, so = s15 + s37;
    float cm = c * (d15 - d37), cp = c * (d15 + d37);
    cpx y[8];
    y[0] = {se + so, 0.f};
    y[1] = {d04 + cm, -(d26 + cp)};
    y[2] = {s04 - s26, s37 - s15};
    y[3] = {d04 - cm, d26 - cp};
    y[4] = {se - so, 0.f};
    y[5] = {d04 - cm, cp - d26};   // conj(y3)
    y[6] = {s04 - s26, s15 - s37}; // conj(y2)
    y[7] = {d04 + cm, d26 + cp};   // conj(y1)
    float sj, cj;
    __sincosf((float)j * 0.01227184630308513f /*2pi/512*/, &sj, &cj);
    cpx wj = {cj, -sj}, tw = {1.f, 0.f};
    float* zb = buf[w];
#pragma unroll
    for (int r = 0; r < 8; ++r) {
      cpx z = cmul(y[r], tw);
      zb[(j * 9 + r) * 2] = z.re;
      zb[(j * 9 + r) * 2 + 1] = z.im;
      tw = cmul(tw, wj);
    }
  }
  __syncthreads();

  // ---- phase 2: complex radix-8 over w (stride 8) + twiddle W64^{i*c}
  cpx yv[8];
  {
    const int r = lane >> 3, i = lane & 7;
    const float* zb = buf[w];
    cpx zz[8];
#pragma unroll
    for (int q = 0; q < 8; ++q) {
      const int j = i + (q << 3);
      zz[q].re = zb[(j * 9 + r) * 2];
      zz[q].im = zb[(j * 9 + r) * 2 + 1];
    }
    cpx t[8];
    radix8(zz, t);
    float si, ci;
    __sincosf((float)i * 0.09817477042468103f /*2pi/64*/, &si, &ci);
    cpx wi = {ci, -si}, tw = {1.f, 0.f};
#pragma unroll
    for (int cc = 0; cc < 8; ++cc) { yv[cc] = cmul(t[cc], tw); tw = cmul(tw, wi); }
  }
  __syncthreads();  // everyone done READING zb before overwrite
  {
    const int r = lane >> 3, i = lane & 7;
    float* yb = buf[w];
#pragma unroll
    for (int cc = 0; cc < 8; ++cc) {
      yb[((r * 8 + cc) * 9 + i) * 2] = yv[cc].re;
      yb[((r * 8 + cc) * 9 + i) * 2 + 1] = yv[cc].im;
    }
  }
  __syncthreads();

  // ---- phase 3: final radix-8 over i -> X[64s + 8c + r], keep k <= 256
  {
    const int r = lane >> 3, cc = lane & 7;
    const float* yb = buf[w];
    cpx yy[8];
#pragma unroll
    for (int i = 0; i < 8; ++i) {
      yy[i].re = yb[((r * 8 + cc) * 9 + i) * 2];
      yy[i].im = yb[((r * 8 + cc) * 9 + i) * 2 + 1];
    }
    cpx X[8];
    radix8(yy, X);
#pragma unroll
    for (int s = 0; s < 8; ++s) {
      const int k = (s << 6) + (cc << 3) + r;
      if (k <= 256) magw[w][k] = sqrtf(X[s].re * X[s].re + X[s].im * X[s].im);
    }
  }
  __syncthreads();

  for (int bin = tid; bin < NBINS; bin += 256) {
    magp[(size_t)blockIdx.x * NBINS + bin] =
        magw[0][bin] + magw[1][bin] + magw[2][bin] + magw[3][bin];
  }
}

// ---------------- Kernel B: per-batch top-5 -> window sizes -------------------
// grid = B_, block = 64. Replicates jax.lax.top_k (descending, ties -> lower idx).
__global__ __launch_bounds__(64) void topk_scale_kernel(const float* __restrict__ magp,
                                                        int* __restrict__ scale) {
  const int b = blockIdx.x;
  const int lane = threadIdx.x;
  __shared__ float m[NBINS];
  for (int i = lane; i < NBINS; i += 64) {
    float s = -1.0f;
    if (i != 0) {
      s = 0.0f;
      for (int c = 0; c < CHUNKS; ++c)
        s += magp[(size_t)(b * CHUNKS + c) * NBINS + i];
    }
    m[i] = s;
  }
  __syncthreads();

  for (int kk = 0; kk < K_; ++kk) {
    float best = -1e30f;
    int bi = NBINS;
    for (int i = lane; i < NBINS; i += 64) {
      const float v = m[i];
      if (v > best || (v == best && i < bi)) { best = v; bi = i; }
    }
    for (int off = 32; off > 0; off >>= 1) {
      const float ov = __shfl_down(best, off);
      const int oi = __shfl_down(bi, off);
      if (ov > best || (ov == best && oi < bi)) { best = ov; bi = oi; }
    }
    bi = __shfl(bi, 0);
    if (lane == 0) {
      // scale = floor(512 / (i * 15/64)) = 32768 / (15*i), exact integer
      int sc = 32768 / (15 * bi);
      sc = sc < 1 ? 1 : (sc > PMAX ? PMAX : sc);
      scale[b * K_ + kk] = sc;
      m[bi] = -1e30f;
    }
    __syncthreads();
  }
}

// ---------------- Kernel C: prefix sum + windowed means -----------------------
// grid = B_*N_, block = 256. One block per (b, n) row.
__global__ __launch_bounds__(256) void trend_kernel(const float* __restrict__ x,
                                                    const int* __restrict__ scale,
                                                    float* __restrict__ out) {
  const int bn = blockIdx.x;
  const int b = bn >> 6;
  const int tid = threadIdx.x;

  __shared__ double bufA[T_];
  __shared__ double bufB[T_];
  __shared__ double P[T_ + 1];

  const float* src = x + ((size_t)bn << 9);
  for (int t = tid; t < T_; t += 256) bufA[t] = (double)src[t];
  __syncthreads();

  double* s = bufA;
  double* d = bufB;
  for (int off = 1; off < T_; off <<= 1) {
    for (int t = tid; t < T_; t += 256) {
      double v = s[t];
      if (t >= off) v += s[t - off];
      d[t] = v;
    }
    __syncthreads();
    double* tmp = s; s = d; d = tmp;
  }
  for (int t = tid; t < T_; t += 256) P[t + 1] = s[t];
  if (tid == 0) P[0] = 0.0;
  __syncthreads();

  const double x0 = (double)src[0];
  const double xl = (double)src[T_ - 1];

  float* outbn = out + (((size_t)bn * K_) << 9);
#pragma unroll
  for (int kk = 0; kk < K_; ++kk) {
    const int k = scale[b * K_ + kk];
    const int p = (k - 1) >> 1;
    const int Lm1 = T_ + 2 * p - k;
    const double invk = 1.0 / (double)k;
    for (int t = tid; t < T_; t += 256) {
      const int tc = t < Lm1 ? t : Lm1;
      const int lo = tc - p;
      const int hi = lo + k;
      const int cl = lo < 0 ? -lo : 0;
      const int cr = hi > T_ ? hi - T_ : 0;
      const int loc = lo < 0 ? 0 : lo;
      const int hic = hi > T_ ? T_ : hi;
      const double sum = P[hic] - P[loc] + (double)cl * x0 + (double)cr * xl;
      outbn[(kk << 9) + t] = (float)(sum * invk);
    }
  }
}

}  // namespace

extern "C" void kernel_launch(void* const* d_in, const int* in_sizes, int n_in,
                              void* d_out, int out_size, void* d_ws, size_t ws_size,
                              hipStream_t stream) {
  const float* x = (const float*)d_in[0];
  float* out = (float*)d_out;

  // mag partials in d_out (2048*257 floats = 2.1 MB); trend_kernel fully
  // overwrites d_out afterwards in stream order, so this is safe scratch.
  float* magp = out;
  int* scale = (int*)d_ws;  // 2.5 KB, must survive while C runs

  hipLaunchKernelGGL(fft_mag_kernel, dim3(B_ * CHUNKS), dim3(256), 0, stream, x, magp);
  hipLaunchKernelGGL(topk_scale_kernel, dim3(B_), dim3(64), 0, stream, magp, scale);
  hipLaunchKernelGGL(trend_kernel, dim3(B_ * N_), dim3(256), 0, stream, x, scale, out);
}

// Round 4
// 46.592 us; speedup vs baseline: 2.6368x; 1.2509x over previous
//
#include <hip/hip_runtime.h>
#include <cmath>

namespace {

constexpr int B_ = 128;
constexpr int N_ = 64;
constexpr int T_ = 512;
constexpr int K_ = 5;
constexpr int NBINS = 257;   // T/2 + 1
constexpr int PMAX = 2184;   // T*T // 120
constexpr int ROWS = 4;      // (b,n) rows per block, 1 per wave
constexpr int CHUNKS = N_ / ROWS;  // 16 mag-partial chunks per batch

struct cpx { float re, im; };
__device__ __forceinline__ cpx cadd(cpx a, cpx b) { return {a.re + b.re, a.im + b.im}; }
__device__ __forceinline__ cpx csub(cpx a, cpx b) { return {a.re - b.re, a.im - b.im}; }
__device__ __forceinline__ cpx cmul(cpx a, cpx b) {
  return {a.re * b.re - a.im * b.im, a.re * b.im + a.im * b.re};
}

// Full complex radix-8 DFT: t[c] = sum_w z[w] * W8^{w*c}, W8 = e^{-2pi i/8}.
__device__ __forceinline__ void radix8(const cpx z[8], cpx t[8]) {
  const float c = 0.70710678118654752f;
  cpx a0 = cadd(z[0], z[4]), a1 = csub(z[0], z[4]);
  cpx a2 = cadd(z[2], z[6]), a3 = csub(z[2], z[6]);
  cpx a4 = cadd(z[1], z[5]), a5 = csub(z[1], z[5]);
  cpx a6 = cadd(z[3], z[7]), a7 = csub(z[3], z[7]);
  cpx b0 = cadd(a0, a2), b1 = csub(a0, a2);
  cpx b2 = cadd(a4, a6), b3 = csub(a4, a6);
  t[0] = cadd(b0, b2);
  t[4] = csub(b0, b2);
  t[2] = {b1.re + b3.im, b1.im - b3.re};   // b1 - i*b3
  t[6] = {b1.re - b3.im, b1.im + b3.re};   // b1 + i*b3
  cpx ua5  = {c * (a5.re + a5.im), c * (a5.im - a5.re)};  // u*a5,  u = c(1-i)
  cpx usa5 = {c * (a5.re - a5.im), c * (a5.re + a5.im)};  // u"*a5, u" = c(1+i)
  cpx ua7  = {c * (a7.re + a7.im), c * (a7.im - a7.re)};
  cpx usa7 = {c * (a7.re - a7.im), c * (a7.re + a7.im)};
  cpx mia3 = {a3.im, -a3.re};  // -i*a3
  cpx pia3 = {-a3.im, a3.re};  // +i*a3
  t[1] = cadd(cadd(a1, ua5), csub(mia3, usa7));
  t[3] = cadd(csub(a1, usa5), cadd(pia3, ua7));
  t[5] = cadd(csub(a1, ua5), cadd(mia3, usa7));
  t[7] = cadd(cadd(a1, usa5), csub(pia3, ua7));
}

// ---------------- Kernel A: radix-8^3 FFT magnitudes --------------------------
// grid = B_*CHUNKS, block = 256 (4 waves, 1 (b,n) row per wave).
__global__ __launch_bounds__(256) void fft_mag_kernel(const float* __restrict__ x,
                                                      float* __restrict__ magp) {
  const int tid = threadIdx.x;
  const int w = tid >> 6;
  const int lane = tid & 63;
  const int row = blockIdx.x * ROWS + w;  // b*64 + n

  __shared__ float buf[ROWS][576 * 2];   // per-wave complex scratch, pad *9
  __shared__ float magw[ROWS][NBINS];

  // ---- phase 1: real radix-8 over v (stride 64) + twiddle W512^{j*r}
  const float* src = x + ((size_t)row << 9);
  float xv[8];
#pragma unroll
  for (int v = 0; v < 8; ++v) xv[v] = src[lane + (v << 6)];
  {
    const int j = lane;
    const float c = 0.70710678118654752f;
    float s04 = xv[0] + xv[4], d04 = xv[0] - xv[4];
    float s26 = xv[2] + xv[6], d26 = xv[2] - xv[6];
    float s15 = xv[1] + xv[5], d15 = xv[1] - xv[5];
    float s37 = xv[3] + xv[7], d37 = xv[3] - xv[7];
    float se = s04 + s26, so = s15 + s37;
    float cm = c * (d15 - d37), cp = c * (d15 + d37);
    cpx y[8];
    y[0] = {se + so, 0.f};
    y[1] = {d04 + cm, -(d26 + cp)};
    y[2] = {s04 - s26, s37 - s15};
    y[3] = {d04 - cm, d26 - cp};
    y[4] = {se - so, 0.f};
    y[5] = {d04 - cm, cp - d26};
    y[6] = {s04 - s26, s15 - s37};
    y[7] = {d04 + cm, d26 + cp};
    float sj, cj;
    __sincosf((float)j * 0.01227184630308513f /*2pi/512*/, &sj, &cj);
    cpx wj = {cj, -sj}, tw = {1.f, 0.f};
    float* zb = buf[w];
#pragma unroll
    for (int r = 0; r < 8; ++r) {
      cpx z = cmul(y[r], tw);
      zb[(j * 9 + r) * 2] = z.re;
      zb[(j * 9 + r) * 2 + 1] = z.im;
      tw = cmul(tw, wj);
    }
  }
  __syncthreads();

  // ---- phase 2: complex radix-8 over w (stride 8) + twiddle W64^{i*c}
  cpx yv[8];
  {
    const int r = lane >> 3, i = lane & 7;
    const float* zb = buf[w];
    cpx zz[8];
#pragma unroll
    for (int q = 0; q < 8; ++q) {
      const int j = i + (q << 3);
      zz[q].re = zb[(j * 9 + r) * 2];
      zz[q].im = zb[(j * 9 + r) * 2 + 1];
    }
    cpx t[8];
    radix8(zz, t);
    float si, ci;
    __sincosf((float)i * 0.09817477042468103f /*2pi/64*/, &si, &ci);
    cpx wi = {ci, -si}, tw = {1.f, 0.f};
#pragma unroll
    for (int cc = 0; cc < 8; ++cc) { yv[cc] = cmul(t[cc], tw); tw = cmul(tw, wi); }
  }
  __syncthreads();
  {
    const int r = lane >> 3, i = lane & 7;
    float* yb = buf[w];
#pragma unroll
    for (int cc = 0; cc < 8; ++cc) {
      yb[((r * 8 + cc) * 9 + i) * 2] = yv[cc].re;
      yb[((r * 8 + cc) * 9 + i) * 2 + 1] = yv[cc].im;
    }
  }
  __syncthreads();

  // ---- phase 3: final radix-8 over i -> X[64s + 8c + r], keep k <= 256
  {
    const int r = lane >> 3, cc = lane & 7;
    const float* yb = buf[w];
    cpx yy[8];
#pragma unroll
    for (int i = 0; i < 8; ++i) {
      yy[i].re = yb[((r * 8 + cc) * 9 + i) * 2];
      yy[i].im = yb[((r * 8 + cc) * 9 + i) * 2 + 1];
    }
    cpx X[8];
    radix8(yy, X);
#pragma unroll
    for (int s = 0; s < 8; ++s) {
      const int k = (s << 6) + (cc << 3) + r;
      if (k <= 256) magw[w][k] = sqrtf(X[s].re * X[s].re + X[s].im * X[s].im);
    }
  }
  __syncthreads();

  for (int bin = tid; bin < NBINS; bin += 256) {
    magp[(size_t)blockIdx.x * NBINS + bin] =
        magw[0][bin] + magw[1][bin] + magw[2][bin] + magw[3][bin];
  }
}

// ---------------- Kernel B: per-batch top-5 -> window sizes -------------------
__global__ __launch_bounds__(64) void topk_scale_kernel(const float* __restrict__ magp,
                                                        int* __restrict__ scale) {
  const int b = blockIdx.x;
  const int lane = threadIdx.x;
  __shared__ float m[NBINS];
  for (int i = lane; i < NBINS; i += 64) {
    float s = -1.0f;
    if (i != 0) {
      s = 0.0f;
      for (int c = 0; c < CHUNKS; ++c)
        s += magp[(size_t)(b * CHUNKS + c) * NBINS + i];
    }
    m[i] = s;
  }
  __syncthreads();

  for (int kk = 0; kk < K_; ++kk) {
    float best = -1e30f;
    int bi = NBINS;
    for (int i = lane; i < NBINS; i += 64) {
      const float v = m[i];
      if (v > best || (v == best && i < bi)) { best = v; bi = i; }
    }
    for (int off = 32; off > 0; off >>= 1) {
      const float ov = __shfl_down(best, off);
      const int oi = __shfl_down(bi, off);
      if (ov > best || (ov == best && oi < bi)) { best = ov; bi = oi; }
    }
    bi = __shfl(bi, 0);
    if (lane == 0) {
      // scale = floor(512 / (i * 15/64)) = 32768 / (15*i), exact integer
      int sc = 32768 / (15 * bi);
      sc = sc < 1 ? 1 : (sc > PMAX ? PMAX : sc);
      scale[b * K_ + kk] = sc;
      m[bi] = -1e30f;
    }
    __syncthreads();
  }
}

// ---------------- Kernel C: single-barrier wave scan + windowed means ---------
// grid = B_*N_/ROWS, block = 256 (4 waves, one (b,n) row per wave).
// Scan phase: lane owns 8 CONSECUTIVE elems (vector loads, register prefix,
// shfl_up wave scan). Output phase: lane owns STRIDED t = lane + 64u so the
// P[] ds_read_b64s are stride-8B across lanes (2-way bank alias = free).
__global__ __launch_bounds__(256) void trend_kernel(const float* __restrict__ x,
                                                    const int* __restrict__ scale,
                                                    float* __restrict__ out) {
  const int w = threadIdx.x >> 6;
  const int lane = threadIdx.x & 63;
  const int bn = blockIdx.x * ROWS + w;  // b*64 + n
  const int b = bn >> 6;

  __shared__ double P[ROWS][T_ + 1];  // 16.4 KB

  const float* src = x + ((size_t)bn << 9);
  const float4 v0 = *reinterpret_cast<const float4*>(src + (lane << 3));
  const float4 v1 = *reinterpret_cast<const float4*>(src + (lane << 3) + 4);

  double e0 = (double)v0.x;
  double e1 = e0 + (double)v0.y;
  double e2 = e1 + (double)v0.z;
  double e3 = e2 + (double)v0.w;
  double e4 = e3 + (double)v1.x;
  double e5 = e4 + (double)v1.y;
  double e6 = e5 + (double)v1.z;
  double e7 = e6 + (double)v1.w;  // inclusive prefix within the 8-chunk

  // exclusive scan of chunk totals across the wave
  double v = e7;
  for (int off = 1; off < 64; off <<= 1) {
    const double o = __shfl_up(v, off);
    if (lane >= off) v += o;
  }
  const double base = v - e7;  // exclusive prefix of this lane's chunk

  double* Pw = P[w];
  if (lane == 0) Pw[0] = 0.0;
  const int p0 = (lane << 3) + 1;
  Pw[p0 + 0] = base + e0;
  Pw[p0 + 1] = base + e1;
  Pw[p0 + 2] = base + e2;
  Pw[p0 + 3] = base + e3;
  Pw[p0 + 4] = base + e4;
  Pw[p0 + 5] = base + e5;
  Pw[p0 + 6] = base + e6;
  Pw[p0 + 7] = base + e7;
  __syncthreads();

  const double x0 = Pw[1];
  const double xl = Pw[T_] - Pw[T_ - 1];

  float* outbn = out + (((size_t)bn * K_) << 9);
#pragma unroll
  for (int kk = 0; kk < K_; ++kk) {
    const int k = scale[b * K_ + kk];
    const int p = (k - 1) >> 1;
    const int Lm1 = T_ + 2 * p - k;  // L - 1
    const double invk = 1.0 / (double)k;
#pragma unroll
    for (int u = 0; u < 8; ++u) {
      const int t = lane + (u << 6);
      const int tc = t < Lm1 ? t : Lm1;
      const int lo = tc - p;       // window = [lo, lo+k) in original coords
      const int hi = lo + k;
      const int cl = lo < 0 ? -lo : 0;        // left edge replications of x[0]
      const int cr = hi > T_ ? hi - T_ : 0;   // right edge replications of x[511]
      const int loc = lo < 0 ? 0 : lo;
      const int hic = hi > T_ ? T_ : hi;
      const double sum = Pw[hic] - Pw[loc] + (double)cl * x0 + (double)cr * xl;
      outbn[(kk << 9) + t] = (float)(sum * invk);
    }
  }
}

}  // namespace

extern "C" void kernel_launch(void* const* d_in, const int* in_sizes, int n_in,
                              void* d_out, int out_size, void* d_ws, size_t ws_size,
                              hipStream_t stream) {
  const float* x = (const float*)d_in[0];
  float* out = (float*)d_out;

  // mag partials in d_out (2048*257 floats = 2.1 MB); trend_kernel fully
  // overwrites d_out afterwards in stream order, so this is safe scratch.
  float* magp = out;
  int* scale = (int*)d_ws;  // 2.5 KB, must survive while C runs

  hipLaunchKernelGGL(fft_mag_kernel, dim3(B_ * CHUNKS), dim3(256), 0, stream, x, magp);
  hipLaunchKernelGGL(topk_scale_kernel, dim3(B_), dim3(64), 0, stream, magp, scale);
  hipLaunchKernelGGL(trend_kernel, dim3(B_ * N_ / ROWS), dim3(256), 0, stream, x, scale, out);
}

// Round 6
// 45.943 us; speedup vs baseline: 2.6740x; 1.0141x over previous
//
#include <hip/hip_runtime.h>
#include <cmath>

namespace {

constexpr int B_ = 128;
constexpr int N_ = 64;
constexpr int T_ = 512;
constexpr int K_ = 5;
constexpr int NBINS = 257;   // T/2 + 1
constexpr int PMAX = 2184;   // T*T // 120
constexpr int ROWS = 4;      // (b,n) rows per block, 1 per wave
constexpr int CHUNKS = N_ / ROWS;  // 16 mag-partial chunks per batch

struct cpx { float re, im; };
__device__ __forceinline__ cpx cadd(cpx a, cpx b) { return {a.re + b.re, a.im + b.im}; }
__device__ __forceinline__ cpx csub(cpx a, cpx b) { return {a.re - b.re, a.im - b.im}; }
__device__ __forceinline__ cpx cmul(cpx a, cpx b) {
  return {a.re * b.re - a.im * b.im, a.re * b.im + a.im * b.re};
}

// Full complex radix-8 DFT: t[c] = sum_w z[w] * W8^{w*c}, W8 = e^{-2pi i/8}.
__device__ __forceinline__ void radix8(const cpx z[8], cpx t[8]) {
  const float c = 0.70710678118654752f;
  cpx a0 = cadd(z[0], z[4]), a1 = csub(z[0], z[4]);
  cpx a2 = cadd(z[2], z[6]), a3 = csub(z[2], z[6]);
  cpx a4 = cadd(z[1], z[5]), a5 = csub(z[1], z[5]);
  cpx a6 = cadd(z[3], z[7]), a7 = csub(z[3], z[7]);
  cpx b0 = cadd(a0, a2), b1 = csub(a0, a2);
  cpx b2 = cadd(a4, a6), b3 = csub(a4, a6);
  t[0] = cadd(b0, b2);
  t[4] = csub(b0, b2);
  t[2] = {b1.re + b3.im, b1.im - b3.re};   // b1 - i*b3
  t[6] = {b1.re - b3.im, b1.im + b3.re};   // b1 + i*b3
  cpx ua5  = {c * (a5.re + a5.im), c * (a5.im - a5.re)};  // u*a5,  u = c(1-i)
  cpx usa5 = {c * (a5.re - a5.im), c * (a5.re + a5.im)};  // u"*a5, u" = c(1+i)
  cpx ua7  = {c * (a7.re + a7.im), c * (a7.im - a7.re)};
  cpx usa7 = {c * (a7.re - a7.im), c * (a7.re + a7.im)};
  cpx mia3 = {a3.im, -a3.re};  // -i*a3
  cpx pia3 = {-a3.im, a3.re};  // +i*a3
  t[1] = cadd(cadd(a1, ua5), csub(mia3, usa7));
  t[3] = cadd(csub(a1, usa5), cadd(pia3, ua7));
  t[5] = cadd(csub(a1, ua5), cadd(mia3, usa7));
  t[7] = cadd(cadd(a1, usa5), csub(pia3, ua7));
}

// ---------------- Kernel A: radix-8^3 FFT magnitudes --------------------------
// grid = B_*CHUNKS, block = 256 (4 waves, 1 (b,n) row per wave).
// LDS scratch is SoA (separate re/im planes) with row stride 9 floats:
// gcd(9,32)=1 -> every phase's lane->bank map is exactly 2-way (free, m136).
// (The old interleaved layout had stride 18: gcd(18,32)=2 -> even banks only,
//  uniform >=4-way conflict on every LDS op.)
__global__ __launch_bounds__(256) void fft_mag_kernel(const float* __restrict__ x,
                                                      float* __restrict__ magp) {
  const int tid = threadIdx.x;
  const int w = tid >> 6;
  const int lane = tid & 63;
  const int row = blockIdx.x * ROWS + w;  // b*64 + n

  __shared__ float bre[ROWS][576];   // 64 rows x stride 9
  __shared__ float bim[ROWS][576];
  __shared__ float magw[ROWS][NBINS];

  // ---- phase 1: real radix-8 over v (stride 64) + twiddle W512^{j*r}
  const float* src = x + ((size_t)row << 9);
  float xv[8];
#pragma unroll
  for (int v = 0; v < 8; ++v) xv[v] = src[lane + (v << 6)];
  {
    const int j = lane;
    const float c = 0.70710678118654752f;
    float s04 = xv[0] + xv[4], d04 = xv[0] - xv[4];
    float s26 = xv[2] + xv[6], d26 = xv[2] - xv[6];
    float s15 = xv[1] + xv[5], d15 = xv[1] - xv[5];
    float s37 = xv[3] + xv[7], d37 = xv[3] - xv[7];
    float se = s04 + s26, so = s15 + s37;
    float cm = c * (d15 - d37), cp = c * (d15 + d37);
    cpx y[8];
    y[0] = {se + so, 0.f};
    y[1] = {d04 + cm, -(d26 + cp)};
    y[2] = {s04 - s26, s37 - s15};
    y[3] = {d04 - cm, d26 - cp};
    y[4] = {se - so, 0.f};
    y[5] = {d04 - cm, cp - d26};
    y[6] = {s04 - s26, s15 - s37};
    y[7] = {d04 + cm, d26 + cp};
    float sj, cj;
    __sincosf((float)j * 0.01227184630308513f /*2pi/512*/, &sj, &cj);
    cpx wj = {cj, -sj}, tw = {1.f, 0.f};
#pragma unroll
    for (int r = 0; r < 8; ++r) {
      cpx z = cmul(y[r], tw);
      bre[w][j * 9 + r] = z.re;
      bim[w][j * 9 + r] = z.im;
      tw = cmul(tw, wj);
    }
  }
  __syncthreads();

  // ---- phase 2: complex radix-8 over w (stride 8) + twiddle W64^{i*c}
  cpx yv[8];
  {
    const int r = lane >> 3, i = lane & 7;
    cpx zz[8];
#pragma unroll
    for (int q = 0; q < 8; ++q) {
      const int idx = (i + (q << 3)) * 9 + r;
      zz[q].re = bre[w][idx];
      zz[q].im = bim[w][idx];
    }
    cpx t[8];
    radix8(zz, t);
    float si, ci;
    __sincosf((float)i * 0.09817477042468103f /*2pi/64*/, &si, &ci);
    cpx wi = {ci, -si}, tw = {1.f, 0.f};
#pragma unroll
    for (int cc = 0; cc < 8; ++cc) { yv[cc] = cmul(t[cc], tw); tw = cmul(tw, wi); }
  }
  __syncthreads();  // all reads of z done before overwrite
  {
    const int r = lane >> 3, i = lane & 7;
#pragma unroll
    for (int cc = 0; cc < 8; ++cc) {
      const int idx = ((r << 3) + cc) * 9 + i;
      bre[w][idx] = yv[cc].re;
      bim[w][idx] = yv[cc].im;
    }
  }
  __syncthreads();

  // ---- phase 3: final radix-8 over i -> X[64s + 8c + r], keep k <= 256
  {
    const int r = lane >> 3, cc = lane & 7;
    cpx yy[8];
#pragma unroll
    for (int i = 0; i < 8; ++i) {
      const int idx = ((r << 3) + cc) * 9 + i;
      yy[i].re = bre[w][idx];
      yy[i].im = bim[w][idx];
    }
    cpx X[8];
    radix8(yy, X);
#pragma unroll
    for (int s = 0; s < 8; ++s) {
      const int k = (s << 6) + (cc << 3) + r;
      if (k <= 256) magw[w][k] = sqrtf(X[s].re * X[s].re + X[s].im * X[s].im);
    }
  }
  __syncthreads();

  for (int bin = tid; bin < NBINS; bin += 256) {
    magp[(size_t)blockIdx.x * NBINS + bin] =
        magw[0][bin] + magw[1][bin] + magw[2][bin] + magw[3][bin];
  }
}

// ---------------- Kernel B: per-batch top-5 -> window sizes -------------------
// Separate dispatch on purpose: cross-workgroup magp handoff inside one
// dispatch raced on XCD L2 non-coherence (R5 failure). Kernel boundary is the
// safe publication point.
__global__ __launch_bounds__(64) void topk_scale_kernel(const float* __restrict__ magp,
                                                        int* __restrict__ scale) {
  const int b = blockIdx.x;
  const int lane = threadIdx.x;
  __shared__ float m[NBINS];
  for (int i = lane; i < NBINS; i += 64) {
    float s = -1.0f;
    if (i != 0) {
      s = 0.0f;
      for (int c = 0; c < CHUNKS; ++c)
        s += magp[(size_t)(b * CHUNKS + c) * NBINS + i];
    }
    m[i] = s;
  }
  __syncthreads();

  for (int kk = 0; kk < K_; ++kk) {
    float best = -1e30f;
    int bi = NBINS;
    for (int i = lane; i < NBINS; i += 64) {
      const float v = m[i];
      if (v > best || (v == best && i < bi)) { best = v; bi = i; }
    }
    for (int off = 32; off > 0; off >>= 1) {
      const float ov = __shfl_down(best, off);
      const int oi = __shfl_down(bi, off);
      if (ov > best || (ov == best && oi < bi)) { best = ov; bi = oi; }
    }
    bi = __shfl(bi, 0);
    if (lane == 0) {
      // scale = floor(512 / (i * 15/64)) = 32768 / (15*i), exact integer
      int sc = 32768 / (15 * bi);
      sc = sc < 1 ? 1 : (sc > PMAX ? PMAX : sc);
      scale[b * K_ + kk] = sc;
      m[bi] = -1e30f;
    }
    __syncthreads();
  }
}

// ---------------- Kernel C: single-barrier wave scan + windowed means ---------
// grid = B_*N_/ROWS, block = 256 (4 waves, one (b,n) row per wave).
__global__ __launch_bounds__(256) void trend_kernel(const float* __restrict__ x,
                                                    const int* __restrict__ scale,
                                                    float* __restrict__ out) {
  const int w = threadIdx.x >> 6;
  const int lane = threadIdx.x & 63;
  const int bn = blockIdx.x * ROWS + w;  // b*64 + n
  const int b = bn >> 6;

  __shared__ double P[ROWS][T_ + 1];  // 16.4 KB

  const float* src = x + ((size_t)bn << 9);
  const float4 v0 = *reinterpret_cast<const float4*>(src + (lane << 3));
  const float4 v1 = *reinterpret_cast<const float4*>(src + (lane << 3) + 4);

  double e0 = (double)v0.x;
  double e1 = e0 + (double)v0.y;
  double e2 = e1 + (double)v0.z;
  double e3 = e2 + (double)v0.w;
  double e4 = e3 + (double)v1.x;
  double e5 = e4 + (double)v1.y;
  double e6 = e5 + (double)v1.z;
  double e7 = e6 + (double)v1.w;  // inclusive prefix within the 8-chunk

  double v = e7;
  for (int off = 1; off < 64; off <<= 1) {
    const double o = __shfl_up(v, off);
    if (lane >= off) v += o;
  }
  const double base = v - e7;  // exclusive prefix of this lane's chunk

  double* Pw = P[w];
  if (lane == 0) Pw[0] = 0.0;
  const int p0 = (lane << 3) + 1;
  Pw[p0 + 0] = base + e0;
  Pw[p0 + 1] = base + e1;
  Pw[p0 + 2] = base + e2;
  Pw[p0 + 3] = base + e3;
  Pw[p0 + 4] = base + e4;
  Pw[p0 + 5] = base + e5;
  Pw[p0 + 6] = base + e6;
  Pw[p0 + 7] = base + e7;
  __syncthreads();

  const double x0 = Pw[1];
  const double xl = Pw[T_] - Pw[T_ - 1];

  float* outbn = out + (((size_t)bn * K_) << 9);
#pragma unroll
  for (int kk = 0; kk < K_; ++kk) {
    const int k = scale[b * K_ + kk];
    const int p = (k - 1) >> 1;
    const int Lm1 = T_ + 2 * p - k;  // L - 1
    const double invk = 1.0 / (double)k;
#pragma unroll
    for (int u = 0; u < 8; ++u) {
      const int t = lane + (u << 6);
      const int tc = t < Lm1 ? t : Lm1;
      const int lo = tc - p;       // window = [lo, lo+k) in original coords
      const int hi = lo + k;
      const int cl = lo < 0 ? -lo : 0;        // left edge replications of x[0]
      const int cr = hi > T_ ? hi - T_ : 0;   // right edge replications of x[511]
      const int loc = lo < 0 ? 0 : lo;
      const int hic = hi > T_ ? T_ : hi;
      const double sum = Pw[hic] - Pw[loc] + (double)cl * x0 + (double)cr * xl;
      outbn[(kk << 9) + t] = (float)(sum * invk);
    }
  }
}

}  // namespace

extern "C" void kernel_launch(void* const* d_in, const int* in_sizes, int n_in,
                              void* d_out, int out_size, void* d_ws, size_t ws_size,
                              hipStream_t stream) {
  const float* x = (const float*)d_in[0];
  float* out = (float*)d_out;

  // mag partials in d_out (2048*257 floats = 2.1 MB); trend_kernel fully
  // overwrites d_out afterwards in stream order, so this is safe scratch.
  float* magp = out;
  int* scale = (int*)d_ws;  // 2.5 KB, must survive while C runs

  hipLaunchKernelGGL(fft_mag_kernel, dim3(B_ * CHUNKS), dim3(256), 0, stream, x, magp);
  hipLaunchKernelGGL(topk_scale_kernel, dim3(B_), dim3(64), 0, stream, magp, scale);
  hipLaunchKernelGGL(trend_kernel, dim3(B_ * N_ / ROWS), dim3(256), 0, stream, x, scale, out);
}

// Round 7
// 45.624 us; speedup vs baseline: 2.6927x; 1.0070x over previous
//
#include <hip/hip_runtime.h>
#include <cmath>

namespace {

constexpr int B_ = 128;
constexpr int N_ = 64;
constexpr int T_ = 512;
constexpr int K_ = 5;
constexpr int NBINS = 257;   // T/2 + 1
constexpr int PMAX = 2184;   // T*T // 120
constexpr int ROWS = 4;      // (b,n) rows per block, 1 per wave
constexpr int CHUNKS = N_ / ROWS;  // 16 mag-partial chunks per batch

struct cpx { float re, im; };
__device__ __forceinline__ cpx cadd(cpx a, cpx b) { return {a.re + b.re, a.im + b.im}; }
__device__ __forceinline__ cpx csub(cpx a, cpx b) { return {a.re - b.re, a.im - b.im}; }
__device__ __forceinline__ cpx cmul(cpx a, cpx b) {
  return {a.re * b.re - a.im * b.im, a.re * b.im + a.im * b.re};
}

// Full complex radix-8 DFT: t[c] = sum_w z[w] * W8^{w*c}, W8 = e^{-2pi i/8}.
__device__ __forceinline__ void radix8(const cpx z[8], cpx t[8]) {
  const float c = 0.70710678118654752f;
  cpx a0 = cadd(z[0], z[4]), a1 = csub(z[0], z[4]);
  cpx a2 = cadd(z[2], z[6]), a3 = csub(z[2], z[6]);
  cpx a4 = cadd(z[1], z[5]), a5 = csub(z[1], z[5]);
  cpx a6 = cadd(z[3], z[7]), a7 = csub(z[3], z[7]);
  cpx b0 = cadd(a0, a2), b1 = csub(a0, a2);
  cpx b2 = cadd(a4, a6), b3 = csub(a4, a6);
  t[0] = cadd(b0, b2);
  t[4] = csub(b0, b2);
  t[2] = {b1.re + b3.im, b1.im - b3.re};   // b1 - i*b3
  t[6] = {b1.re - b3.im, b1.im + b3.re};   // b1 + i*b3
  cpx ua5  = {c * (a5.re + a5.im), c * (a5.im - a5.re)};  // u*a5,  u = c(1-i)
  cpx usa5 = {c * (a5.re - a5.im), c * (a5.re + a5.im)};  // u"*a5, u" = c(1+i)
  cpx ua7  = {c * (a7.re + a7.im), c * (a7.im - a7.re)};
  cpx usa7 = {c * (a7.re - a7.im), c * (a7.re + a7.im)};
  cpx mia3 = {a3.im, -a3.re};  // -i*a3
  cpx pia3 = {-a3.im, a3.re};  // +i*a3
  t[1] = cadd(cadd(a1, ua5), csub(mia3, usa7));
  t[3] = cadd(csub(a1, usa5), cadd(pia3, ua7));
  t[5] = cadd(csub(a1, ua5), cadd(mia3, usa7));
  t[7] = cadd(cadd(a1, usa5), csub(pia3, ua7));
}

// ---------------- Kernel A: radix-8^3 FFT magnitudes --------------------------
// grid = B_*CHUNKS, block = 256 (4 waves, 1 (b,n) row per wave).
// __launch_bounds__(256, 6): cap VGPR at ~85 so >=6 waves/SIMD are resident
// (theory: bare launch_bounds let VGPR exceed ~170 -> 2-3 waves/SIMD -> grid
//  executed in ~3 serial rounds -> 24 us for ~8 us of issued work).
// LDS: SoA stride-9 planes (conflict-free); mag results reuse the bre plane
// (dead after phase-3 reads) so LDS = 18.4 KB never caps residency below VGPR.
__global__ __launch_bounds__(256, 6) void fft_mag_kernel(const float* __restrict__ x,
                                                         float* __restrict__ magp) {
  const int tid = threadIdx.x;
  const int w = tid >> 6;
  const int lane = tid & 63;
  const int row = blockIdx.x * ROWS + w;  // b*64 + n

  __shared__ float bre[ROWS][576];   // 64 rows x stride 9; phase-3 output reuses [0..256]
  __shared__ float bim[ROWS][576];

  // ---- phase 1: real radix-8 over v (stride 64) + twiddle W512^{j*r}
  const float* src = x + ((size_t)row << 9);
  float xv[8];
#pragma unroll
  for (int v = 0; v < 8; ++v) xv[v] = src[lane + (v << 6)];
  {
    const int j = lane;
    const float c = 0.70710678118654752f;
    float s04 = xv[0] + xv[4], d04 = xv[0] - xv[4];
    float s26 = xv[2] + xv[6], d26 = xv[2] - xv[6];
    float s15 = xv[1] + xv[5], d15 = xv[1] - xv[5];
    float s37 = xv[3] + xv[7], d37 = xv[3] - xv[7];
    float se = s04 + s26, so = s15 + s37;
    float cm = c * (d15 - d37), cp = c * (d15 + d37);
    cpx y[8];
    y[0] = {se + so, 0.f};
    y[1] = {d04 + cm, -(d26 + cp)};
    y[2] = {s04 - s26, s37 - s15};
    y[3] = {d04 - cm, d26 - cp};
    y[4] = {se - so, 0.f};
    y[5] = {d04 - cm, cp - d26};
    y[6] = {s04 - s26, s15 - s37};
    y[7] = {d04 + cm, d26 + cp};
    float sj, cj;
    __sincosf((float)j * 0.01227184630308513f /*2pi/512*/, &sj, &cj);
    cpx wj = {cj, -sj}, tw = {1.f, 0.f};
#pragma unroll
    for (int r = 0; r < 8; ++r) {
      cpx z = cmul(y[r], tw);
      bre[w][j * 9 + r] = z.re;
      bim[w][j * 9 + r] = z.im;
      tw = cmul(tw, wj);
    }
  }
  __syncthreads();

  // ---- phase 2: complex radix-8 over w (stride 8) + twiddle W64^{i*c}
  cpx yv[8];
  {
    const int r = lane >> 3, i = lane & 7;
    cpx zz[8];
#pragma unroll
    for (int q = 0; q < 8; ++q) {
      const int idx = (i + (q << 3)) * 9 + r;
      zz[q].re = bre[w][idx];
      zz[q].im = bim[w][idx];
    }
    cpx t[8];
    radix8(zz, t);
    float si, ci;
    __sincosf((float)i * 0.09817477042468103f /*2pi/64*/, &si, &ci);
    cpx wi = {ci, -si}, tw = {1.f, 0.f};
#pragma unroll
    for (int cc = 0; cc < 8; ++cc) { yv[cc] = cmul(t[cc], tw); tw = cmul(tw, wi); }
  }
  __syncthreads();  // all reads of z done before overwrite
  {
    const int r = lane >> 3, i = lane & 7;
#pragma unroll
    for (int cc = 0; cc < 8; ++cc) {
      const int idx = ((r << 3) + cc) * 9 + i;
      bre[w][idx] = yv[cc].re;
      bim[w][idx] = yv[cc].im;
    }
  }
  __syncthreads();

  // ---- phase 3: final radix-8 over i -> X[64s + 8c + r], keep k <= 256.
  // Output mags overwrite bre[w][0..256]: all 16 yy reads precede the writes
  // in program order and waves touch only their own plane -> race-free.
  {
    const int r = lane >> 3, cc = lane & 7;
    cpx yy[8];
#pragma unroll
    for (int i = 0; i < 8; ++i) {
      const int idx = ((r << 3) + cc) * 9 + i;
      yy[i].re = bre[w][idx];
      yy[i].im = bim[w][idx];
    }
    cpx X[8];
    radix8(yy, X);
#pragma unroll
    for (int s = 0; s < 8; ++s) {
      const int k = (s << 6) + (cc << 3) + r;
      const float mg = sqrtf(X[s].re * X[s].re + X[s].im * X[s].im);
      if (k <= 256) bre[w][k] = mg;
    }
  }
  __syncthreads();

  for (int bin = tid; bin < NBINS; bin += 256) {
    magp[(size_t)blockIdx.x * NBINS + bin] =
        bre[0][bin] + bre[1][bin] + bre[2][bin] + bre[3][bin];
  }
}

// ---------------- Kernel B: per-batch top-5 -> window sizes -------------------
// Separate dispatch on purpose: cross-workgroup magp handoff inside one
// dispatch raced on XCD L2 non-coherence (R5 failure). Kernel boundary is the
// safe publication point.
__global__ __launch_bounds__(64) void topk_scale_kernel(const float* __restrict__ magp,
                                                        int* __restrict__ scale) {
  const int b = blockIdx.x;
  const int lane = threadIdx.x;
  __shared__ float m[NBINS];
  for (int i = lane; i < NBINS; i += 64) {
    float s = -1.0f;
    if (i != 0) {
      s = 0.0f;
      for (int c = 0; c < CHUNKS; ++c)
        s += magp[(size_t)(b * CHUNKS + c) * NBINS + i];
    }
    m[i] = s;
  }
  __syncthreads();

  for (int kk = 0; kk < K_; ++kk) {
    float best = -1e30f;
    int bi = NBINS;
    for (int i = lane; i < NBINS; i += 64) {
      const float v = m[i];
      if (v > best || (v == best && i < bi)) { best = v; bi = i; }
    }
    for (int off = 32; off > 0; off >>= 1) {
      const float ov = __shfl_down(best, off);
      const int oi = __shfl_down(bi, off);
      if (ov > best || (ov == best && oi < bi)) { best = ov; bi = oi; }
    }
    bi = __shfl(bi, 0);
    if (lane == 0) {
      // scale = floor(512 / (i * 15/64)) = 32768 / (15*i), exact integer
      int sc = 32768 / (15 * bi);
      sc = sc < 1 ? 1 : (sc > PMAX ? PMAX : sc);
      scale[b * K_ + kk] = sc;
      m[bi] = -1e30f;
    }
    __syncthreads();
  }
}

// ---------------- Kernel C: single-barrier wave scan + windowed means ---------
// grid = B_*N_/ROWS, block = 256 (4 waves, one (b,n) row per wave).
__global__ __launch_bounds__(256) void trend_kernel(const float* __restrict__ x,
                                                    const int* __restrict__ scale,
                                                    float* __restrict__ out) {
  const int w = threadIdx.x >> 6;
  const int lane = threadIdx.x & 63;
  const int bn = blockIdx.x * ROWS + w;  // b*64 + n
  const int b = bn >> 6;

  __shared__ double P[ROWS][T_ + 1];  // 16.4 KB

  const float* src = x + ((size_t)bn << 9);
  const float4 v0 = *reinterpret_cast<const float4*>(src + (lane << 3));
  const float4 v1 = *reinterpret_cast<const float4*>(src + (lane << 3) + 4);

  double e0 = (double)v0.x;
  double e1 = e0 + (double)v0.y;
  double e2 = e1 + (double)v0.z;
  double e3 = e2 + (double)v0.w;
  double e4 = e3 + (double)v1.x;
  double e5 = e4 + (double)v1.y;
  double e6 = e5 + (double)v1.z;
  double e7 = e6 + (double)v1.w;  // inclusive prefix within the 8-chunk

  double v = e7;
  for (int off = 1; off < 64; off <<= 1) {
    const double o = __shfl_up(v, off);
    if (lane >= off) v += o;
  }
  const double base = v - e7;  // exclusive prefix of this lane's chunk

  double* Pw = P[w];
  if (lane == 0) Pw[0] = 0.0;
  const int p0 = (lane << 3) + 1;
  Pw[p0 + 0] = base + e0;
  Pw[p0 + 1] = base + e1;
  Pw[p0 + 2] = base + e2;
  Pw[p0 + 3] = base + e3;
  Pw[p0 + 4] = base + e4;
  Pw[p0 + 5] = base + e5;
  Pw[p0 + 6] = base + e6;
  Pw[p0 + 7] = base + e7;
  __syncthreads();

  const double x0 = Pw[1];
  const double xl = Pw[T_] - Pw[T_ - 1];

  float* outbn = out + (((size_t)bn * K_) << 9);
#pragma unroll
  for (int kk = 0; kk < K_; ++kk) {
    const int k = scale[b * K_ + kk];
    const int p = (k - 1) >> 1;
    const int Lm1 = T_ + 2 * p - k;  // L - 1
    const double invk = 1.0 / (double)k;
#pragma unroll
    for (int u = 0; u < 8; ++u) {
      const int t = lane + (u << 6);
      const int tc = t < Lm1 ? t : Lm1;
      const int lo = tc - p;       // window = [lo, lo+k) in original coords
      const int hi = lo + k;
      const int cl = lo < 0 ? -lo : 0;        // left edge replications of x[0]
      const int cr = hi > T_ ? hi - T_ : 0;   // right edge replications of x[511]
      const int loc = lo < 0 ? 0 : lo;
      const int hic = hi > T_ ? T_ : hi;
      const double sum = Pw[hic] - Pw[loc] + (double)cl * x0 + (double)cr * xl;
      outbn[(kk << 9) + t] = (float)(sum * invk);
    }
  }
}

}  // namespace

extern "C" void kernel_launch(void* const* d_in, const int* in_sizes, int n_in,
                              void* d_out, int out_size, void* d_ws, size_t ws_size,
                              hipStream_t stream) {
  const float* x = (const float*)d_in[0];
  float* out = (float*)d_out;

  // mag partials in d_out (2048*257 floats = 2.1 MB); trend_kernel fully
  // overwrites d_out afterwards in stream order, so this is safe scratch.
  float* magp = out;
  int* scale = (int*)d_ws;  // 2.5 KB, must survive while C runs

  hipLaunchKernelGGL(fft_mag_kernel, dim3(B_ * CHUNKS), dim3(256), 0, stream, x, magp);
  hipLaunchKernelGGL(topk_scale_kernel, dim3(B_), dim3(64), 0, stream, magp, scale);
  hipLaunchKernelGGL(trend_kernel, dim3(B_ * N_ / ROWS), dim3(256), 0, stream, x, scale, out);
}